// Round 8
// baseline (160.897 us; speedup 1.0000x reference)
//
#include <hip/hip_runtime.h>

#define T_LEN 32768
#define DIM   300
#define NCH   75     // DIM/4 float4 chunks per row
#define NP    5      // superdiagonal entries
#define TB    16     // window starts per block
#define ROWS  20     // TB + NP - 1 vals rows per block

__device__ __forceinline__ float fast_sigmoid(float z) {
    return 1.0f / (1.0f + __expf(-z));
}

// Accumulate 5 superdiagonal dots for one float4 chunk c of the row.
#define ACC(xv, c)                                                              \
    {                                                                           \
        const float4 w0 = *reinterpret_cast<const float4*>(&lds_w[0][4 * (c)]); \
        const float4 w1 = *reinterpret_cast<const float4*>(&lds_w[1][4 * (c)]); \
        const float4 w2 = *reinterpret_cast<const float4*>(&lds_w[2][4 * (c)]); \
        const float4 w3 = *reinterpret_cast<const float4*>(&lds_w[3][4 * (c)]); \
        const float4 w4 = *reinterpret_cast<const float4*>(&lds_w[4][4 * (c)]); \
        a0 += (xv).x * w0.x + (xv).y * w0.y + (xv).z * w0.z + (xv).w * w0.w;    \
        a1 += (xv).x * w1.x + (xv).y * w1.y + (xv).z * w1.z + (xv).w * w1.w;    \
        a2 += (xv).x * w2.x + (xv).y * w2.y + (xv).z * w2.z + (xv).w * w2.w;    \
        a3 += (xv).x * w3.x + (xv).y * w3.y + (xv).z * w3.z + (xv).w * w3.w;    \
        a4 += (xv).x * w4.x + (xv).y * w4.y + (xv).z * w4.z + (xv).w * w4.w;    \
    }

__global__ __launch_bounds__(256, 8) void fused_kernel(
    const int*   __restrict__ doc,   // [T]
    const float* __restrict__ emb,   // [VOCAB, 300]
    const float* __restrict__ w,     // [6, 6, 300]
    const float* __restrict__ b,     // [6, 6]
    float*       __restrict__ out)   // [1]
{
    __shared__ float lds_w[NP][DIM];
    __shared__ float lds_b[NP];
    __shared__ float lds_v[ROWS][NP];

    const int tid = threadIdx.x;
    const int g   = tid >> 4;       // 16 groups of 16 lanes
    const int sub = tid & 15;
    const int t0  = blockIdx.x * TB;

    // ---- Row A: issue gather loads FIRST so HBM latency overlaps w-staging ----
    const int  tA = t0 + g;
    const bool vA = (tA < T_LEN);
    const float* __restrict__ xrowA = emb + (size_t)(vA ? doc[tA] : 0) * DIM;

    const float4 xa0 = *reinterpret_cast<const float4*>(xrowA + 4 * (sub));
    const float4 xa1 = *reinterpret_cast<const float4*>(xrowA + 4 * (sub + 16));
    const float4 xa2 = *reinterpret_cast<const float4*>(xrowA + 4 * (sub + 32));
    const float4 xa3 = *reinterpret_cast<const float4*>(xrowA + 4 * (sub + 48));
    float4 xa4 = make_float4(0.f, 0.f, 0.f, 0.f);
    if (sub < NCH - 64)
        xa4 = *reinterpret_cast<const float4*>(xrowA + 4 * (sub + 64));

    // ---- Stage superdiagonal w rows (flat row 7i+1) into LDS ----
    for (int c = tid; c < NP * NCH; c += 256) {
        const int i  = c / NCH;
        const int cc = c - i * NCH;
        *reinterpret_cast<float4*>(&lds_w[i][4 * cc]) =
            *reinterpret_cast<const float4*>(w + (size_t)(7 * i + 1) * DIM + 4 * cc);
    }
    if (tid < NP) lds_b[tid] = b[7 * tid + 1];
    __syncthreads();

    // ---- Row A dots ----
    {
        float a0 = 0.f, a1 = 0.f, a2 = 0.f, a3 = 0.f, a4 = 0.f;
        ACC(xa0, sub);
        ACC(xa1, sub + 16);
        ACC(xa2, sub + 32);
        ACC(xa3, sub + 48);
        if (sub < NCH - 64) ACC(xa4, sub + 64);
        #pragma unroll
        for (int off = 8; off >= 1; off >>= 1) {
            a0 += __shfl_xor(a0, off);
            a1 += __shfl_xor(a1, off);
            a2 += __shfl_xor(a2, off);
            a3 += __shfl_xor(a3, off);
            a4 += __shfl_xor(a4, off);
        }
        if (sub < NP) {
            const float a = (sub == 0) ? a0 : (sub == 1) ? a1 : (sub == 2) ? a2
                           : (sub == 3) ? a3 : a4;
            lds_v[g][sub] = vA ? fast_sigmoid(a + lds_b[sub]) : 0.f;
        }
    }

    // ---- Row B (halo): groups 0..3 == wave 0, so shuffles stay wave-uniform ----
    if (g < ROWS - TB) {
        const int  tB = t0 + TB + g;
        const bool vB = (tB < T_LEN);
        const float* __restrict__ xrowB = emb + (size_t)(vB ? doc[tB] : 0) * DIM;

        float a0 = 0.f, a1 = 0.f, a2 = 0.f, a3 = 0.f, a4 = 0.f;
        const float4 xb0 = *reinterpret_cast<const float4*>(xrowB + 4 * (sub));
        const float4 xb1 = *reinterpret_cast<const float4*>(xrowB + 4 * (sub + 16));
        const float4 xb2 = *reinterpret_cast<const float4*>(xrowB + 4 * (sub + 32));
        const float4 xb3 = *reinterpret_cast<const float4*>(xrowB + 4 * (sub + 48));
        ACC(xb0, sub);
        ACC(xb1, sub + 16);
        ACC(xb2, sub + 32);
        ACC(xb3, sub + 48);
        if (sub < NCH - 64) {
            const float4 xb4 = *reinterpret_cast<const float4*>(xrowB + 4 * (sub + 64));
            ACC(xb4, sub + 64);
        }
        #pragma unroll
        for (int off = 8; off >= 1; off >>= 1) {
            a0 += __shfl_xor(a0, off);
            a1 += __shfl_xor(a1, off);
            a2 += __shfl_xor(a2, off);
            a3 += __shfl_xor(a3, off);
            a4 += __shfl_xor(a4, off);
        }
        if (sub < NP) {
            const float a = (sub == 0) ? a0 : (sub == 1) ? a1 : (sub == 2) ? a2
                           : (sub == 3) ? a3 : a4;
            lds_v[TB + g][sub] = vB ? fast_sigmoid(a + lds_b[sub]) : 0.f;
        }
    }
    __syncthreads();

    // ---- Window products for this block's 16 starts; wave 0 only ----
    if (tid < 64) {
        float p = 0.f;
        const int s = t0 + tid;
        if (tid < TB && s <= T_LEN - NP) {
            p = lds_v[tid + 0][0] * lds_v[tid + 1][1] * lds_v[tid + 2][2]
              * lds_v[tid + 3][3] * lds_v[tid + 4][4];
        }
        #pragma unroll
        for (int off = 32; off >= 1; off >>= 1) p += __shfl_xor(p, off);
        if (tid == 0) atomicAdd(out, p);
    }
}

extern "C" void kernel_launch(void* const* d_in, const int* in_sizes, int n_in,
                              void* d_out, int out_size, void* d_ws, size_t ws_size,
                              hipStream_t stream) {
    const int*   doc = (const int*)  d_in[0];
    const float* emb = (const float*)d_in[1];
    const float* w   = (const float*)d_in[2];
    const float* b   = (const float*)d_in[3];
    float*       out = (float*)d_out;

    hipMemsetAsync(out, 0, sizeof(float), stream);
    fused_kernel<<<T_LEN / TB, 256, 0, stream>>>(doc, emb, w, b, out);
}

// Round 9
// 104.020 us; speedup vs baseline: 1.5468x; 1.5468x over previous
//
#include <hip/hip_runtime.h>

#define T_LEN 32768
#define DIM   300
#define NCH   75     // DIM/4 float4 chunks per row
#define NP    5      // superdiagonal entries

__device__ __forceinline__ float fast_sigmoid(float z) {
    return 1.0f / (1.0f + __expf(-z));
}

// Each 16-lane group computes the 5 superdiagonal dot products for one t.
// vals stored SoA: vals[i][t] = sigmoid(w[i,i+1].x_t + b[i,i+1])
__global__ __launch_bounds__(256) void vals_kernel(
    const int*   __restrict__ doc,   // [T]
    const float* __restrict__ emb,   // [VOCAB, 300]
    const float* __restrict__ w,     // [6, 6, 300]
    const float* __restrict__ b,     // [6, 6]
    float*       __restrict__ vals)  // ws: [5][T]
{
    __shared__ float lds_w[NP][DIM];
    __shared__ float lds_b[NP];

    const int tid = threadIdx.x;
    const int g   = tid >> 4;       // group 0..15 within block -> one t each
    const int sub = tid & 15;
    const int t   = blockIdx.x * 16 + g;

    // ---- Prefetch: issue the gather loads FIRST so their HBM latency ----
    // ---- overlaps the w-staging below instead of following the barrier ----
    const float* __restrict__ xrow = emb + (size_t)doc[t] * DIM;
    const float4 x0 = *reinterpret_cast<const float4*>(xrow + 4 * (sub));
    const float4 x1 = *reinterpret_cast<const float4*>(xrow + 4 * (sub + 16));
    const float4 x2 = *reinterpret_cast<const float4*>(xrow + 4 * (sub + 32));
    const float4 x3 = *reinterpret_cast<const float4*>(xrow + 4 * (sub + 48));
    float4 x4 = make_float4(0.f, 0.f, 0.f, 0.f);
    if (sub < NCH - 64)
        x4 = *reinterpret_cast<const float4*>(xrow + 4 * (sub + 64));

    // ---- Stage superdiagonal w rows (flat row 7i+1) into LDS via float4 ----
    for (int c = tid; c < NP * NCH; c += 256) {
        const int i  = c / NCH;
        const int cc = c - i * NCH;
        *reinterpret_cast<float4*>(&lds_w[i][4 * cc]) =
            *reinterpret_cast<const float4*>(w + (size_t)(7 * i + 1) * DIM + 4 * cc);
    }
    if (tid < NP) lds_b[tid] = b[7 * tid + 1];
    __syncthreads();

    float a0 = 0.f, a1 = 0.f, a2 = 0.f, a3 = 0.f, a4 = 0.f;
    #define ACC(xv, c)                                                              \
        {                                                                           \
            const float4 w0 = *reinterpret_cast<const float4*>(&lds_w[0][4 * (c)]); \
            const float4 w1 = *reinterpret_cast<const float4*>(&lds_w[1][4 * (c)]); \
            const float4 w2 = *reinterpret_cast<const float4*>(&lds_w[2][4 * (c)]); \
            const float4 w3 = *reinterpret_cast<const float4*>(&lds_w[3][4 * (c)]); \
            const float4 w4 = *reinterpret_cast<const float4*>(&lds_w[4][4 * (c)]); \
            a0 += (xv).x * w0.x + (xv).y * w0.y + (xv).z * w0.z + (xv).w * w0.w;    \
            a1 += (xv).x * w1.x + (xv).y * w1.y + (xv).z * w1.z + (xv).w * w1.w;    \
            a2 += (xv).x * w2.x + (xv).y * w2.y + (xv).z * w2.z + (xv).w * w2.w;    \
            a3 += (xv).x * w3.x + (xv).y * w3.y + (xv).z * w3.z + (xv).w * w3.w;    \
            a4 += (xv).x * w4.x + (xv).y * w4.y + (xv).z * w4.z + (xv).w * w4.w;    \
        }
    ACC(x0, sub);
    ACC(x1, sub + 16);
    ACC(x2, sub + 32);
    ACC(x3, sub + 48);
    if (sub < NCH - 64) ACC(x4, sub + 64);
    #undef ACC

    // 16-lane butterfly (xor offsets < 16 stay inside the group)
    #pragma unroll
    for (int off = 8; off >= 1; off >>= 1) {
        a0 += __shfl_xor(a0, off);
        a1 += __shfl_xor(a1, off);
        a2 += __shfl_xor(a2, off);
        a3 += __shfl_xor(a3, off);
        a4 += __shfl_xor(a4, off);
    }

    if (sub < NP) {
        const float a = (sub == 0) ? a0 : (sub == 1) ? a1 : (sub == 2) ? a2
                       : (sub == 3) ? a3 : a4;
        vals[sub * T_LEN + t] = fast_sigmoid(a + lds_b[sub]);
    }
}

__global__ __launch_bounds__(256) void reduce_kernel(
    const float* __restrict__ vals,  // [5][T]
    float*       __restrict__ out)
{
    const int s = blockIdx.x * 256 + threadIdx.x;
    float p = 0.f;
    if (s <= T_LEN - NP) {
        p = vals[s]
          * vals[1 * T_LEN + s + 1]
          * vals[2 * T_LEN + s + 2]
          * vals[3 * T_LEN + s + 3]
          * vals[4 * T_LEN + s + 4];
    }
    #pragma unroll
    for (int off = 32; off >= 1; off >>= 1) p += __shfl_xor(p, off);

    __shared__ float partial[4];
    if ((threadIdx.x & 63) == 0) partial[threadIdx.x >> 6] = p;
    __syncthreads();
    if (threadIdx.x == 0)
        atomicAdd(out, partial[0] + partial[1] + partial[2] + partial[3]);
}

extern "C" void kernel_launch(void* const* d_in, const int* in_sizes, int n_in,
                              void* d_out, int out_size, void* d_ws, size_t ws_size,
                              hipStream_t stream) {
    const int*   doc = (const int*)  d_in[0];
    const float* emb = (const float*)d_in[1];
    const float* w   = (const float*)d_in[2];
    const float* b   = (const float*)d_in[3];
    float*       out = (float*)d_out;
    float*       vals = (float*)d_ws;   // 5*T*4 = 640 KB

    hipMemsetAsync(out, 0, sizeof(float), stream);

    vals_kernel<<<T_LEN / 16, 256, 0, stream>>>(doc, emb, w, b, vals);
    reduce_kernel<<<(T_LEN + 255) / 256, 256, 0, stream>>>(vals, out);
}